// Round 1
// baseline (209.592 us; speedup 1.0000x reference)
//
#include <hip/hip_runtime.h>

// YOLO loss, fp32. predictions: (batch,7,7,13), target: (batch,7,7,8), out: scalar.
// Memory-bound reduction: ~135 MB read -> ~21 us roofline at 6.3 TB/s.

static constexpr int PRED_C = 13;   // 5*B + C
static constexpr int TGT_C  = 8;    // 1 + 4 + 3
static constexpr float L_NOOBJ = 0.5f;
static constexpr float L_COORD = 5.0f;
static constexpr float EPSI = 1e-6f;

__global__ void zero_kernel(float* out) {
    if (threadIdx.x == 0) out[0] = 0.0f;
}

__device__ __forceinline__ float iou_f(float ax, float ay, float aw, float ah,
                                       float bx, float by, float bw, float bh) {
    float ax1 = ax - aw * 0.5f, ax2 = ax + aw * 0.5f;
    float ay1 = ay - ah * 0.5f, ay2 = ay + ah * 0.5f;
    float bx1 = bx - bw * 0.5f, bx2 = bx + bw * 0.5f;
    float by1 = by - bh * 0.5f, by2 = by + bh * 0.5f;
    float iw = fmaxf(fminf(ax2, bx2) - fmaxf(ax1, bx1), 0.0f);
    float ih = fmaxf(fminf(ay2, by2) - fmaxf(ay1, by1), 0.0f);
    float inter = iw * ih;
    float uni = (ax2 - ax1) * (ay2 - ay1) + (bx2 - bx1) * (by2 - by1) - inter;
    return inter / (uni + EPSI);
}

__global__ __launch_bounds__(256) void yolo_loss(const float* __restrict__ pred,
                                                 const float* __restrict__ tgt,
                                                 float* __restrict__ out,
                                                 long long ncells, float inv_batch) {
    // Stage 256 cells x 13 floats of predictions in LDS (coalesced float4 global
    // loads; stride-13 LDS reads are 2 lanes/bank = conflict-free on wave64).
    __shared__ float sp[256 * PRED_C];      // 13312 B
    __shared__ float wsum[4];

    const int t = threadIdx.x;
    const long long cell0 = (long long)blockIdx.x * 256;

    {
        const float4* gp = (const float4*)(pred + cell0 * PRED_C);
        float4* lp = (float4*)sp;
        // floats remaining from this tile's base, in float4 units (tail guard)
        long long limit4 = ((ncells - cell0) * PRED_C) / 4;
        #pragma unroll
        for (int i = 0; i < 4; ++i) {
            int idx = t + i * 256;                 // 0..1023, need 0..831
            if (idx < 832 && idx < limit4) lp[idx] = gp[idx];
        }
    }
    __syncthreads();

    float v = 0.0f;
    const long long cell = cell0 + t;
    if (cell < ncells) {
        const float* p = sp + t * PRED_C;
        // target: 2x float4 straight from global (32B-aligned, coalesced enough)
        const float4* gt = (const float4*)(tgt + cell * TGT_C);
        float4 t0 = gt[0];
        float4 t1 = gt[1];

        float m  = (t0.x == 1.0f) ? 1.0f : 0.0f;
        float tx = t0.y, ty = t0.z, tw = t0.w, th = t1.x;
        float tc0 = t1.y, tc1 = t1.z, tc2 = t1.w;

        float b1c = p[0],  b1x = p[1],  b1y = p[2],  b1w = p[3], b1h = p[4];
        float b2c = p[5],  b2x = p[6],  b2y = p[7],  b2w = p[8], b2h = p[9];
        float pc0 = p[10], pc1 = p[11], pc2 = p[12];

        float i1 = iou_f(b1x, b1y, b1w, b1h, tx, ty, tw, th);
        float i2 = iou_f(b2x, b2y, b2w, b2h, tx, ty, tw, th);
        bool pick1 = i1 > i2;
        float iou = pick1 ? i1 : i2;
        float sc  = pick1 ? b1c : b2c;
        float sx  = pick1 ? b1x : b2x;
        float sy  = pick1 ? b1y : b2y;
        float sw  = pick1 ? b1w : b2w;
        float sh  = pick1 ? b1h : b2h;
        float uc  = pick1 ? b2c : b1c;   // unselected confidence

        float dx = sx - tx, dy = sy - ty;
        // sign(w)*sqrt(|w|): copysign(sqrt(|w|), w) matches jnp.sign semantics
        // (w==0 -> 0) for all finite inputs.
        float dw = copysignf(sqrtf(fabsf(sw)), sw) - sqrtf(tw);
        float dh = copysignf(sqrtf(fabsf(sh)), sh) - sqrtf(th);
        float l_coord = dx * dx + dy * dy + dw * dw + dh * dh;

        float doj = sc - iou;
        float d0 = pc0 - tc0, d1 = pc1 - tc1, d2 = pc2 - tc2;
        float l_cls = d0 * d0 + d1 * d1 + d2 * d2;
        float l_noobj = m * uc * uc + (1.0f - m) * (b1c * b1c + b2c * b2c);

        v = m * (L_COORD * l_coord + doj * doj + l_cls) + L_NOOBJ * l_noobj;
    }

    // wave64 shuffle reduction
    #pragma unroll
    for (int off = 32; off > 0; off >>= 1)
        v += __shfl_down(v, off, 64);
    if ((t & 63) == 0) wsum[t >> 6] = v;
    __syncthreads();
    if (t == 0) {
        float s = (wsum[0] + wsum[1]) + (wsum[2] + wsum[3]);
        atomicAdd(out, s * inv_batch);
    }
}

extern "C" void kernel_launch(void* const* d_in, const int* in_sizes, int n_in,
                              void* d_out, int out_size, void* d_ws, size_t ws_size,
                              hipStream_t stream) {
    const float* pred = (const float*)d_in[0];
    const float* tgt  = (const float*)d_in[1];
    float* out = (float*)d_out;

    long long ncells = (long long)in_sizes[1] / TGT_C;   // batch*S*S
    long long batch  = ncells / 49;                      // S=7
    float inv_batch  = 1.0f / (float)batch;
    int nblocks = (int)((ncells + 255) / 256);           // 6272 for batch=32768

    zero_kernel<<<1, 64, 0, stream>>>(out);
    yolo_loss<<<nblocks, 256, 0, stream>>>(pred, tgt, out, ncells, inv_batch);
}

// Round 2
// 162.921 us; speedup vs baseline: 1.2865x; 1.2865x over previous
//
#include <hip/hip_runtime.h>

// YOLO loss, fp32. predictions: (batch,7,7,13), target: (batch,7,7,8), out: scalar.
// R1: latency-bound at 96us (HBM 8.8%, VALU 9%) -> persistent blocks, double-buffered
// async global->LDS staging (global_load_lds width=16), deterministic 2-kernel reduce.

static constexpr int PRED_C = 13;   // 5*B + C
static constexpr int TGT_C  = 8;    // 1 + 4 + 3
static constexpr float L_NOOBJ = 0.5f;
static constexpr float L_COORD = 5.0f;
static constexpr float EPSI = 1e-6f;

static constexpr int NBLOCKS = 1024;          // 4 blocks/CU on 256 CUs
static constexpr int TILE    = 256;           // cells per tile (1 cell/thread)
static constexpr int TILE_F  = TILE * PRED_C; // 3328 floats = 13312 B per buffer

typedef const __attribute__((address_space(1))) unsigned int* gp1_t;
typedef __attribute__((address_space(3))) unsigned int*       lp3_t;

__device__ __forceinline__ float iou_f(float ax, float ay, float aw, float ah,
                                       float bx, float by, float bw, float bh) {
    float ax1 = ax - aw * 0.5f, ax2 = ax + aw * 0.5f;
    float ay1 = ay - ah * 0.5f, ay2 = ay + ah * 0.5f;
    float bx1 = bx - bw * 0.5f, bx2 = bx + bw * 0.5f;
    float by1 = by - bh * 0.5f, by2 = by + bh * 0.5f;
    float iw = fmaxf(fminf(ax2, bx2) - fmaxf(ax1, bx1), 0.0f);
    float ih = fmaxf(fminf(ay2, by2) - fmaxf(ay1, by1), 0.0f);
    float inter = iw * ih;
    float uni = (ax2 - ax1) * (ay2 - ay1) + (bx2 - bx1) * (by2 - by1) - inter;
    return inter / (uni + EPSI);
}

__global__ __launch_bounds__(256) void yolo_main(const float* __restrict__ pred,
                                                 const float* __restrict__ tgt,
                                                 float* __restrict__ partial,
                                                 long long ncells, long long ntiles) {
    __shared__ float sp[2][TILE_F];   // 2 x 13312 B double buffer
    __shared__ float wsum[4];

    const int t = threadIdx.x;
    const int wave = t >> 6;

    float acc = 0.0f;
    float4 tg0 = make_float4(0.f, 0.f, 0.f, 0.f);
    float4 tg1 = tg0;

    // Stage one 256-cell tile of predictions (832 float4) into sp[b].
    // Fast path: async direct-to-LDS DMA. LDS dest is wave-uniform base +
    // lane*16 -> layout is the natural contiguous order (no padding).
    auto stage = [&](long long tl, int b) {
        const float* gbase = pred + tl * (long long)TILE_F;
        if ((tl + 1) * TILE <= ncells) {
#pragma unroll
            for (int r = 0; r < 3; ++r) {
                int f4 = r * 256 + t;
                __builtin_amdgcn_global_load_lds(
                    (gp1_t)(gbase + (size_t)f4 * 4),
                    (lp3_t)(&sp[b][(r * 256 + wave * 64) * 4]),
                    16, 0, 0);
            }
            if (wave == 0) {                       // round 3: 64 float4 tail
                int f4 = 3 * 256 + t;              // t in [0,64)
                __builtin_amdgcn_global_load_lds(
                    (gp1_t)(gbase + (size_t)f4 * 4),
                    (lp3_t)(&sp[b][3 * 256 * 4]),
                    16, 0, 0);
            }
        } else {                                   // tail tile: guarded scalar
            long long c = tl * TILE + t;
            if (c < ncells) {
#pragma unroll
                for (int i = 0; i < PRED_C; ++i)
                    sp[b][t * PRED_C + i] = pred[c * PRED_C + i];
            }
        }
    };
    auto loadtgt = [&](long long tl) {             // prefetch target into regs
        long long c = tl * TILE + t;
        if (c < ncells) {
            const float4* g = (const float4*)(tgt + c * TGT_C);
            tg0 = g[0];
            tg1 = g[1];
        }
    };

    long long tile = blockIdx.x;
    int b = 0;
    if (tile < ntiles) {
        stage(tile, 0);
        loadtgt(tile);
    }

    while (tile < ntiles) {
        __syncthreads();   // implicit vmcnt(0) drain: sp[b] + tg regs ready
        float4 t0 = tg0, t1 = tg1;
        long long next = tile + NBLOCKS;
        if (next < ntiles) {   // prefetch next tile while computing this one
            stage(next, b ^ 1);
            loadtgt(next);
        }

        long long cell = tile * TILE + t;
        if (cell < ncells) {
            const float* p = &sp[b][t * PRED_C];   // stride-13: 2-way bank alias = free

            float m  = (t0.x == 1.0f) ? 1.0f : 0.0f;
            float tx = t0.y, ty = t0.z, tw = t0.w, th = t1.x;

            float b1c = p[0],  b1x = p[1],  b1y = p[2],  b1w = p[3], b1h = p[4];
            float b2c = p[5],  b2x = p[6],  b2y = p[7],  b2w = p[8], b2h = p[9];

            float i1 = iou_f(b1x, b1y, b1w, b1h, tx, ty, tw, th);
            float i2 = iou_f(b2x, b2y, b2w, b2h, tx, ty, tw, th);
            bool pick1 = i1 > i2;
            float iou = pick1 ? i1 : i2;
            float sc  = pick1 ? b1c : b2c;
            float sx  = pick1 ? b1x : b2x;
            float sy  = pick1 ? b1y : b2y;
            float sw  = pick1 ? b1w : b2w;
            float sh  = pick1 ? b1h : b2h;
            float uc  = pick1 ? b2c : b1c;

            float dx = sx - tx, dy = sy - ty;
            float dw = copysignf(sqrtf(fabsf(sw)), sw) - sqrtf(tw);
            float dh = copysignf(sqrtf(fabsf(sh)), sh) - sqrtf(th);
            float l_coord = dx * dx + dy * dy + dw * dw + dh * dh;

            float doj = sc - iou;
            float d0 = p[10] - t1.y, d1 = p[11] - t1.z, d2 = p[12] - t1.w;
            float l_cls = d0 * d0 + d1 * d1 + d2 * d2;
            float l_noobj = m * uc * uc + (1.0f - m) * (b1c * b1c + b2c * b2c);

            acc += m * (L_COORD * l_coord + doj * doj + l_cls) + L_NOOBJ * l_noobj;
        }

        b ^= 1;
        tile = next;
    }

    // block reduction -> one partial per block (deterministic, no atomics)
#pragma unroll
    for (int off = 32; off > 0; off >>= 1)
        acc += __shfl_down(acc, off, 64);
    if ((t & 63) == 0) wsum[wave] = acc;
    __syncthreads();
    if (t == 0) partial[blockIdx.x] = (wsum[0] + wsum[1]) + (wsum[2] + wsum[3]);
}

__global__ __launch_bounds__(256) void yolo_reduce(const float* __restrict__ partial,
                                                   float* __restrict__ out,
                                                   float inv_batch) {
    __shared__ float wsum[4];
    int t = threadIdx.x;
    float v = partial[t] + partial[t + 256] + partial[t + 512] + partial[t + 768];
#pragma unroll
    for (int off = 32; off > 0; off >>= 1)
        v += __shfl_down(v, off, 64);
    if ((t & 63) == 0) wsum[t >> 6] = v;
    __syncthreads();
    if (t == 0) out[0] = ((wsum[0] + wsum[1]) + (wsum[2] + wsum[3])) * inv_batch;
}

extern "C" void kernel_launch(void* const* d_in, const int* in_sizes, int n_in,
                              void* d_out, int out_size, void* d_ws, size_t ws_size,
                              hipStream_t stream) {
    const float* pred = (const float*)d_in[0];
    const float* tgt  = (const float*)d_in[1];
    float* out = (float*)d_out;
    float* partial = (float*)d_ws;                       // NBLOCKS floats

    long long ncells = (long long)in_sizes[1] / TGT_C;   // batch*S*S
    long long batch  = ncells / 49;                      // S=7
    float inv_batch  = 1.0f / (float)batch;
    long long ntiles = (ncells + TILE - 1) / TILE;       // 6272

    yolo_main<<<NBLOCKS, 256, 0, stream>>>(pred, tgt, partial, ncells, ntiles);
    yolo_reduce<<<1, 256, 0, stream>>>(partial, out, inv_batch);
}